// Round 1
// baseline (995.526 us; speedup 1.0000x reference)
//
#include <hip/hip_runtime.h>

#define N_NODES 200000
#define N_EDGES 6400000
#define N_GRAPHS 1024
#define F_IN 16
#define H1 8
#define H2 16
#define STEPS 4

// ---------------- SAGEConv1: y1 = x @ W1l.T (pre-transform before aggregate) ----
__global__ void k_y1(const float* __restrict__ x, const float* __restrict__ W1l,
                     float* __restrict__ y1) {
    int n = blockIdx.x * blockDim.x + threadIdx.x;
    if (n >= N_NODES) return;
    float xv[F_IN];
#pragma unroll
    for (int k = 0; k < F_IN; k++) xv[k] = x[(long long)n * F_IN + k];
#pragma unroll
    for (int j = 0; j < H1; j++) {
        float s = 0.f;
#pragma unroll
        for (int k = 0; k < F_IN; k++) s += W1l[j * F_IN + k] * xv[k];
        y1[(long long)n * H1 + j] = s;
    }
}

// ---------------- edge scatter: agg[dst] += val[src], 8 feats; optional degree ---
__global__ void k_edge_scatter(const int* __restrict__ src, const int* __restrict__ dst,
                               const float* __restrict__ val, float* __restrict__ agg,
                               float* __restrict__ deg /* may be null */) {
    long long t = (long long)blockIdx.x * blockDim.x + threadIdx.x;
    long long e = t >> 3;
    int f = (int)(t & 7);
    if (e >= N_EDGES) return;
    int s = src[e], d = dst[e];
    atomicAdd(&agg[(long long)d * H1 + f], val[(long long)s * H1 + f]);
    if (deg && f == 0) atomicAdd(&deg[d], 1.0f);
}

// ---------------- h1 = relu(agg1/deg + b1l + x @ W1r.T) -------------------------
__global__ void k_h1(const float* __restrict__ x, const float* __restrict__ agg1,
                     const float* __restrict__ deg, const float* __restrict__ b1l,
                     const float* __restrict__ W1r, float* __restrict__ h1) {
    int n = blockIdx.x * blockDim.x + threadIdx.x;
    if (n >= N_NODES) return;
    float inv = 1.0f / fmaxf(deg[n], 1.0f);
    float xv[F_IN];
#pragma unroll
    for (int k = 0; k < F_IN; k++) xv[k] = x[(long long)n * F_IN + k];
#pragma unroll
    for (int j = 0; j < H1; j++) {
        float s = agg1[(long long)n * H1 + j] * inv + b1l[j];
#pragma unroll
        for (int k = 0; k < F_IN; k++) s += W1r[j * F_IN + k] * xv[k];
        h1[(long long)n * H1 + j] = fmaxf(s, 0.0f);
    }
}

// ---------------- h2 = relu((agg2/deg) @ W2l.T + b2l + h1 @ W2r.T) ---------------
__global__ void k_h2(const float* __restrict__ h1, const float* __restrict__ agg2,
                     const float* __restrict__ deg, const float* __restrict__ b2l,
                     const float* __restrict__ W2l, const float* __restrict__ W2r,
                     float* __restrict__ h2) {
    int n = blockIdx.x * blockDim.x + threadIdx.x;
    if (n >= N_NODES) return;
    float inv = 1.0f / fmaxf(deg[n], 1.0f);
    float av[H1], hv[H1];
#pragma unroll
    for (int k = 0; k < H1; k++) {
        av[k] = agg2[(long long)n * H1 + k] * inv;
        hv[k] = h1[(long long)n * H1 + k];
    }
#pragma unroll
    for (int j = 0; j < H2; j++) {
        float s = b2l[j];
#pragma unroll
        for (int k = 0; k < H1; k++) s += W2l[j * H1 + k] * av[k] + W2r[j * H1 + k] * hv[k];
        h2[(long long)n * H2 + j] = fmaxf(s, 0.0f);
    }
}

// ---------------- graph segment pointers from sorted batch -----------------------
__global__ void k_ptr(const int* __restrict__ batch, int* __restrict__ ptr) {
    int n = blockIdx.x * blockDim.x + threadIdx.x;
    if (n >= N_NODES) return;
    int b = batch[n];
    int bp = (n == 0) ? -1 : batch[n - 1];
    for (int g = bp + 1; g <= b; g++) ptr[g] = n;
    if (n == N_NODES - 1) {
        for (int g = b + 1; g <= N_GRAPHS; g++) ptr[g] = N_NODES;
    }
}

// ---------------- Set2Set + final FC: one block per graph ------------------------
__global__ __launch_bounds__(256) void k_set2set(
    const float* __restrict__ h2, const int* __restrict__ ptr,
    const float* __restrict__ Wih, const float* __restrict__ Whh,
    const float* __restrict__ bih, const float* __restrict__ bhh,
    const float* __restrict__ Wfc, const float* __restrict__ bfc,
    float* __restrict__ out) {
    int b = blockIdx.x;
    int start = ptr[b], end = ptr[b + 1], cnt = end - start;
    __shared__ float sh[H2], sc[H2], sq[2 * H2], sg[4 * H2];
    __shared__ float red[4][17];
    __shared__ float s_emax, s_asum, s_r[H2];
    int tid = threadIdx.x;
    int wid = tid >> 6, lane = tid & 63;

    if (tid < H2) { sh[tid] = 0.f; sc[tid] = 0.f; }
    if (tid < 2 * H2) sq[tid] = 0.f;
    __syncthreads();

    for (int step = 0; step < STEPS; step++) {
        // gates = q_star @ Wih.T + bih + h @ Whh.T + bhh   (64 outputs)
        if (tid < 64) {
            float g = bih[tid] + bhh[tid];
#pragma unroll
            for (int k = 0; k < 2 * H2; k++) g += Wih[tid * (2 * H2) + k] * sq[k];
#pragma unroll
            for (int k = 0; k < H2; k++) g += Whh[tid * H2 + k] * sh[k];
            sg[tid] = g;
        }
        __syncthreads();
        if (tid < H2) {
            // torch gate order: i, f, g, o
            float ig = 1.f / (1.f + expf(-sg[tid]));
            float fg = 1.f / (1.f + expf(-sg[H2 + tid]));
            float gg = tanhf(sg[2 * H2 + tid]);
            float og = 1.f / (1.f + expf(-sg[3 * H2 + tid]));
            float cc = fg * sc[tid] + ig * gg;
            sc[tid] = cc;
            sh[tid] = og * tanhf(cc);
        }
        __syncthreads();

        // pass 1: e = <h2[n], h>, segment max
        float lmax = -3.0e38f;
        for (int i = start + tid; i < end; i += 256) {
            float e = 0.f;
#pragma unroll
            for (int k = 0; k < H2; k++) e += h2[(long long)i * H2 + k] * sh[k];
            lmax = fmaxf(lmax, e);
        }
        for (int off = 32; off; off >>= 1) lmax = fmaxf(lmax, __shfl_down(lmax, off));
        if (lane == 0) red[wid][0] = lmax;
        __syncthreads();
        if (tid == 0) {
            float m = red[0][0];
            for (int w = 1; w < 4; w++) m = fmaxf(m, red[w][0]);
            s_emax = m;
        }
        __syncthreads();
        float emax = s_emax;

        // pass 2: a = exp(e - emax); asum; r = sum a * h2[n]
        float asum = 0.f, rloc[H2];
#pragma unroll
        for (int k = 0; k < H2; k++) rloc[k] = 0.f;
        for (int i = start + tid; i < end; i += 256) {
            float hv[H2];
            float e = 0.f;
#pragma unroll
            for (int k = 0; k < H2; k++) { hv[k] = h2[(long long)i * H2 + k]; e += hv[k] * sh[k]; }
            float a = expf(e - emax);
            asum += a;
#pragma unroll
            for (int k = 0; k < H2; k++) rloc[k] += a * hv[k];
        }
        for (int off = 32; off; off >>= 1) {
            asum += __shfl_down(asum, off);
#pragma unroll
            for (int k = 0; k < H2; k++) rloc[k] += __shfl_down(rloc[k], off);
        }
        if (lane == 0) {
            red[wid][16] = asum;
#pragma unroll
            for (int k = 0; k < H2; k++) red[wid][k] = rloc[k];
        }
        __syncthreads();
        if (tid < 17) {
            float s = red[0][tid] + red[1][tid] + red[2][tid] + red[3][tid];
            if (tid == 16) s_asum = s; else s_r[tid] = s;
        }
        __syncthreads();
        if (tid < H2) {
            float rr = (cnt > 0 && s_asum > 0.f) ? s_r[tid] / s_asum : 0.0f;
            sq[tid] = sh[tid];        // q = h
            sq[H2 + tid] = rr;        // r
        }
        __syncthreads();
    }

    // out = q_star @ Wfc.T + bfc   (2 outputs)
    if (tid < 2) {
        float s = bfc[tid];
#pragma unroll
        for (int k = 0; k < 2 * H2; k++) s += Wfc[tid * (2 * H2) + k] * sq[k];
        out[b * 2 + tid] = s;
    }
}

extern "C" void kernel_launch(void* const* d_in, const int* in_sizes, int n_in,
                              void* d_out, int out_size, void* d_ws, size_t ws_size,
                              hipStream_t stream) {
    const float* x   = (const float*)d_in[0];
    const int*   ei  = (const int*)d_in[1];
    const int*   src = ei;
    const int*   dst = ei + N_EDGES;
    const int*   batch = (const int*)d_in[2];
    const float* W1l = (const float*)d_in[3];
    const float* b1l = (const float*)d_in[4];
    const float* W1r = (const float*)d_in[5];
    const float* W2l = (const float*)d_in[6];
    const float* b2l = (const float*)d_in[7];
    const float* W2r = (const float*)d_in[8];
    const float* Wih = (const float*)d_in[9];
    const float* Whh = (const float*)d_in[10];
    const float* bih = (const float*)d_in[11];
    const float* bhh = (const float*)d_in[12];
    const float* Wfc = (const float*)d_in[13];
    const float* bfc = (const float*)d_in[14];
    float* out = (float*)d_out;

    // workspace layout (floats)
    float* ws = (float*)d_ws;
    float* agg1 = ws;                                  // N_NODES*H1
    float* agg2 = agg1 + (size_t)N_NODES * H1;         // N_NODES*H1
    float* deg  = agg2 + (size_t)N_NODES * H1;         // N_NODES
    float* y1   = deg + N_NODES;                       // N_NODES*H1
    float* h1   = y1 + (size_t)N_NODES * H1;           // N_NODES*H1
    float* h2   = h1 + (size_t)N_NODES * H1;           // N_NODES*H2
    int*   ptr  = (int*)(h2 + (size_t)N_NODES * H2);   // N_GRAPHS+1

    // zero the accumulators (contiguous region agg1|agg2|deg)
    size_t zero_bytes = ((size_t)N_NODES * H1 * 2 + N_NODES) * sizeof(float);
    hipMemsetAsync(agg1, 0, zero_bytes, stream);

    int nb_node = (N_NODES + 255) / 256;
    k_y1<<<nb_node, 256, 0, stream>>>(x, W1l, y1);

    long long et = (long long)N_EDGES * 8;
    int nb_edge = (int)((et + 255) / 256);
    k_edge_scatter<<<nb_edge, 256, 0, stream>>>(src, dst, y1, agg1, deg);

    k_h1<<<nb_node, 256, 0, stream>>>(x, agg1, deg, b1l, W1r, h1);

    k_edge_scatter<<<nb_edge, 256, 0, stream>>>(src, dst, h1, agg2, nullptr);

    k_h2<<<nb_node, 256, 0, stream>>>(h1, agg2, deg, b2l, W2l, W2r, h2);

    k_ptr<<<nb_node, 256, 0, stream>>>(batch, ptr);

    k_set2set<<<N_GRAPHS, 256, 0, stream>>>(h2, ptr, Wih, Whh, bih, bhh, Wfc, bfc, out);
}